// Round 1
// baseline (372.029 us; speedup 1.0000x reference)
//
#include <hip/hip_runtime.h>
#include <stdint.h>

// Forbid FMA contraction globally (HIP default is -ffp-contract=fast, which
// would change IoU rounding vs the numpy reference and can flip iou>0.45).
#pragma clang fp contract(off)

#define BATCH 32
#define NPRED 24564
#define NCLS 21
#define ROWCH 33          // 21 conf + 4 loc + 8 anchor
#define NBINS 512
#define CAP 2048
#define TOPK 200
#define NMS_OUT 50

// ---- workspace layout (bytes) ----
#define HIST_BYTES   (BATCH*NCLS*NBINS*4)            // 1,376,256
#define COUNTS_OFF   (HIST_BYTES)
#define COUNTS_BYTES (BATCH*NCLS*4)                  // 2,688
#define THRESH_OFF   (COUNTS_OFF + COUNTS_BYTES)
#define THRESH_BYTES (BATCH*NCLS*4)
#define CAND_OFF     (THRESH_OFF + THRESH_BYTES)     // 1,381,632 (8B aligned)
#define CAND_BYTES   (BATCH*NCLS*CAP*8)              // 11,010,048
#define ROWS_OFF     (CAND_OFF + CAND_BYTES)
#define ROWS_BYTES   (BATCH*NCLS*NMS_OUT*6*4)        // 806,400
// total ~12.6 MB

// Histogram of conf scores > 0.5 per (b, class). Scores are uniform^2 in
// [0,1); values in (0.5,1.0) have bits in (0x3F000000, 0x3F800000) -> the
// bit pattern is monotone in value, so (bits-0x3F000000)>>14 is a monotone
// 512-bin index.
__global__ __launch_bounds__(256) void k_hist(const float* __restrict__ pred,
                                              int* __restrict__ hist) {
  __shared__ int lh[NCLS * NBINS];     // 43 KB
  const int b = blockIdx.y, s = blockIdx.x, tid = threadIdx.x;
  for (int i = tid; i < NCLS * NBINS; i += 256) lh[i] = 0;
  __syncthreads();
  const int EB = NPRED * ROWCH;        // 810,612 (divisible by 4)
  const int F4 = EB / 4;               // 202,653 float4s per batch
  const int per = (F4 + 31) / 32;
  int f0 = s * per;
  int f1 = f0 + per; if (f1 > F4) f1 = F4;
  const float4* p4 = (const float4*)(pred + (size_t)b * EB);
  for (int f = f0 + tid; f < f1; f += 256) {
    float4 v = p4[f];
    unsigned r = (4u * (unsigned)f) % 33u;
    float vv[4] = {v.x, v.y, v.z, v.w};
#pragma unroll
    for (int k = 0; k < 4; ++k) {
      if (r < NCLS && vv[k] > 0.5f) {
        unsigned bin = (__float_as_uint(vv[k]) - 0x3F000000u) >> 14;
        if (bin > 511u) bin = 511u;
        atomicAdd(&lh[r * NBINS + bin], 1);
      }
      r++; if (r == 33u) r = 0u;
    }
  }
  __syncthreads();
  int* gh = hist + (size_t)b * NCLS * NBINS;
  for (int i = tid; i < NCLS * NBINS; i += 256) {
    int v = lh[i];
    if (v) atomicAdd(&gh[i], v);
  }
}

// Per (b,c): find the highest bin t such that count of scores in bins>=t is
// >= 200 (t=0 if fewer than 200 candidates exist). Superset-of-top-200 proof:
// bins are monotone in score, so the 200 largest scores all lie in bins>=t.
__global__ void k_thresh(const int* __restrict__ hist, int* __restrict__ thresh) {
  int bc = blockIdx.x * 256 + threadIdx.x;
  if (bc >= BATCH * NCLS) return;
  const int* h = hist + (size_t)bc * NBINS;
  int cum = 0, t = 0;
  for (int bin = NBINS - 1; bin >= 0; --bin) {
    cum += h[bin];
    if (cum >= TOPK) { t = bin; break; }
  }
  thresh[bc] = t;
}

// Gather candidates with bin >= threshold into per-(b,c) lists.
// Key = (~score_bits << 32) | row_index: ascending sort == descending score,
// ties -> lower index first (exactly lax.top_k semantics).
__global__ __launch_bounds__(256) void k_gather(const float* __restrict__ pred,
                                                const int* __restrict__ thresh,
                                                int* __restrict__ counts,
                                                unsigned long long* __restrict__ cand) {
  __shared__ int lthr[NCLS];
  const int b = blockIdx.y, s = blockIdx.x, tid = threadIdx.x;
  if (tid < NCLS) lthr[tid] = thresh[b * NCLS + tid];
  __syncthreads();
  const int EB = NPRED * ROWCH;
  const int F4 = EB / 4;
  const int per = (F4 + 31) / 32;
  int f0 = s * per;
  int f1 = f0 + per; if (f1 > F4) f1 = F4;
  const float4* p4 = (const float4*)(pred + (size_t)b * EB);
  for (int f = f0 + tid; f < f1; f += 256) {
    float4 v = p4[f];
    unsigned e = 4u * (unsigned)f;
    unsigned q = e / 33u;              // row (anchor) index
    unsigned r = e - q * 33u;          // channel
    float vv[4] = {v.x, v.y, v.z, v.w};
#pragma unroll
    for (int k = 0; k < 4; ++k) {
      if (r < NCLS && vv[k] > 0.5f) {
        unsigned fb = __float_as_uint(vv[k]);
        unsigned bin = (fb - 0x3F000000u) >> 14;
        if (bin > 511u) bin = 511u;
        if ((int)bin >= lthr[r]) {
          int pos = atomicAdd(&counts[b * NCLS + r], 1);
          if (pos < CAP)
            cand[((size_t)(b * NCLS + r)) * CAP + pos] =
                ((unsigned long long)(~fb) << 32) | (unsigned long long)q;
        }
      }
      r++; if (r == 33u) { r = 0u; q++; }
    }
  }
}

// One block per (b,c): exact sort of gathered candidates, decode top-200
// boxes, sequential 50-step NMS matching the reference scan, emit 50 rows.
__global__ __launch_bounds__(256) void k_nms(const float* __restrict__ pred,
                                             const int* __restrict__ counts,
                                             const unsigned long long* __restrict__ cand,
                                             float* __restrict__ rows) {
  __shared__ unsigned long long keys[CAP];   // 16 KB
  __shared__ float bx[TOPK][4];
  __shared__ float sc[TOPK];
  __shared__ unsigned long long red[4];
  __shared__ unsigned long long bestC;

  const int bc = blockIdx.x, tid = threadIdx.x;
  const int b = bc / NCLS, c = bc % NCLS;
  int m = counts[bc]; if (m > CAP) m = CAP;
  int p2 = 256; while (p2 < m) p2 <<= 1;
  const unsigned long long* cd = cand + (size_t)bc * CAP;
  for (int i = tid; i < p2; i += 256) keys[i] = (i < m) ? cd[i] : ~0ULL;
  __syncthreads();
  // bitonic ascending (key = (~score_bits, index))
  for (int k = 2; k <= p2; k <<= 1) {
    for (int j = k >> 1; j > 0; j >>= 1) {
      for (int i = tid; i < p2; i += 256) {
        int ixj = i ^ j;
        if (ixj > i) {
          unsigned long long a = keys[i], bb = keys[ixj];
          if ((a > bb) == ((i & k) == 0)) { keys[i] = bb; keys[ixj] = a; }
        }
      }
      __syncthreads();
    }
  }
  // decode boxes for the top-200 (exact rounding: no contraction)
  int mm = m < TOPK ? m : TOPK;
  if (tid < TOPK) {
    if (tid < mm) {
      unsigned long long key = keys[tid];
      unsigned n = (unsigned)key;
      float score = __uint_as_float(~(unsigned)(key >> 32));
      const float* p = pred + ((size_t)b * NPRED + n) * ROWCH;
      float l0 = p[21], l1 = p[22], l2 = p[23], l3 = p[24];
      float acx = p[25], acy = p[26], aw = p[27], ah = p[28];
      float v0 = p[29], v1 = p[30], v2 = p[31], v3 = p[32];
      float cx = __fadd_rn(__fmul_rn(__fmul_rn(l0, aw), v0), acx);
      float cy = __fadd_rn(__fmul_rn(__fmul_rn(l1, ah), v1), acy);
      float w  = __fmul_rn(expf(__fmul_rn(l2, v2)), aw);
      float h  = __fmul_rn(expf(__fmul_rn(l3, v3)), ah);
      float hw = __fmul_rn(0.5f, w), hh = __fmul_rn(0.5f, h);
      bx[tid][0] = __fmul_rn(__fsub_rn(cx, hw), 512.0f);
      bx[tid][1] = __fmul_rn(__fsub_rn(cy, hh), 512.0f);
      bx[tid][2] = __fmul_rn(__fadd_rn(cx, hw), 512.0f);
      bx[tid][3] = __fmul_rn(__fadd_rn(cy, hh), 512.0f);
      sc[tid] = score;
    } else {
      bx[tid][0] = bx[tid][1] = bx[tid][2] = bx[tid][3] = 0.f;
      sc[tid] = -1.0f;   // matches the reference's masked -1.0 fill slots
    }
  }
  __syncthreads();

  for (int it = 0; it < NMS_OUT; ++it) {
    // argmax over sc[0..199], first-max-index tie break (jnp.argmax)
    unsigned long long comb = 0ULL;
    if (tid < TOPK) {
      unsigned u = __float_as_uint(sc[tid]);
      u = (u & 0x80000000u) ? ~u : (u | 0x80000000u);   // order-preserving
      comb = ((unsigned long long)u << 32) | (unsigned long long)(0xFFFFFFFFu - (unsigned)tid);
    }
    for (int off = 32; off > 0; off >>= 1) {
      unsigned long long o = __shfl_xor(comb, off);
      if (o > comb) comb = o;
    }
    if ((tid & 63) == 0) red[tid >> 6] = comb;
    __syncthreads();
    if (tid == 0) {
      unsigned long long best = red[0];
      for (int w = 1; w < 4; ++w) if (red[w] > best) best = red[w];
      bestC = best;
    }
    __syncthreads();
    unsigned long long best = bestC;
    int bi = (int)(0xFFFFFFFFu - (unsigned)best);
    unsigned ou = (unsigned)(best >> 32);
    unsigned su = (ou & 0x80000000u) ? (ou ^ 0x80000000u) : ~ou;
    float bscore = __uint_as_float(su);
    bool valid = bscore > 0.0f;
    float bi0 = bx[bi][0], bi1 = bx[bi][1], bi2 = bx[bi][2], bi3 = bx[bi][3];
    if (valid && tid < TOPK) {
      float x1 = fmaxf(bi0, bx[tid][0]);
      float y1 = fmaxf(bi1, bx[tid][1]);
      float x2 = fminf(bi2, bx[tid][2]);
      float y2 = fminf(bi3, bx[tid][3]);
      float iw = fmaxf(__fsub_rn(x2, x1), 0.0f);
      float ih = fmaxf(__fsub_rn(y2, y1), 0.0f);
      float inter = __fmul_rn(iw, ih);
      float areaA = __fmul_rn(__fsub_rn(bi2, bi0), __fsub_rn(bi3, bi1));
      float areaB = __fmul_rn(__fsub_rn(bx[tid][2], bx[tid][0]),
                              __fsub_rn(bx[tid][3], bx[tid][1]));
      float den = __fadd_rn(areaA, areaB);
      den = __fsub_rn(den, inter);
      den = __fadd_rn(den, 1e-8f);
      float iou = __fdiv_rn(inter, den);
      if (iou > 0.45f || tid == bi) sc[tid] = -1.0f;
    }
    if (tid == 0) {
      float* rr = rows + ((size_t)bc * NMS_OUT + it) * 6;
      if (valid) {
        rr[0] = (float)c; rr[1] = bscore;
        rr[2] = bi0; rr[3] = bi1; rr[4] = bi2; rr[5] = bi3;
      } else {
        rr[0] = rr[1] = rr[2] = rr[3] = rr[4] = rr[5] = 0.f;
      }
    }
    __syncthreads();
  }
}

// Per batch: top-200 of the 1050 rows by score (ties -> lower row index),
// then gather the selected rows to the output.
__global__ __launch_bounds__(256) void k_final(const float* __restrict__ rows,
                                               float* __restrict__ out) {
  __shared__ unsigned long long fk[2048];    // 16 KB
  const int b = blockIdx.x, tid = threadIdx.x;
  const int NR = NCLS * NMS_OUT;             // 1050
  const float* rb = rows + (size_t)b * NR * 6;
  for (int i = tid; i < 2048; i += 256) {
    if (i < NR) {
      unsigned fb = __float_as_uint(rb[i * 6 + 1]);  // score >= +0.0 always
      fk[i] = ((unsigned long long)(~fb) << 32) | (unsigned long long)i;
    } else fk[i] = ~0ULL;
  }
  __syncthreads();
  for (int k = 2; k <= 2048; k <<= 1) {
    for (int j = k >> 1; j > 0; j >>= 1) {
      for (int i = tid; i < 2048; i += 256) {
        int ixj = i ^ j;
        if (ixj > i) {
          unsigned long long a = fk[i], bb = fk[ixj];
          if ((a > bb) == ((i & k) == 0)) { fk[i] = bb; fk[ixj] = a; }
        }
      }
      __syncthreads();
    }
  }
  float* ob = out + (size_t)b * TOPK * 6;
  for (int q = tid; q < TOPK * 6; q += 256) {
    int k = q / 6, col = q % 6;
    unsigned r = (unsigned)fk[k];
    ob[q] = rb[r * 6 + col];
  }
}

extern "C" void kernel_launch(void* const* d_in, const int* in_sizes, int n_in,
                              void* d_out, int out_size, void* d_ws, size_t ws_size,
                              hipStream_t stream) {
  const float* pred = (const float*)d_in[0];
  float* out = (float*)d_out;
  char* ws = (char*)d_ws;
  int* hist = (int*)(ws);
  int* counts = (int*)(ws + COUNTS_OFF);
  int* thresh = (int*)(ws + THRESH_OFF);
  unsigned long long* cand = (unsigned long long*)(ws + CAND_OFF);
  float* rows = (float*)(ws + ROWS_OFF);

  // zero hist + counts (adjacent -> one memset); ws is re-poisoned each call
  hipMemsetAsync(ws, 0, HIST_BYTES + COUNTS_BYTES, stream);
  k_hist  <<<dim3(32, BATCH), 256, 0, stream>>>(pred, hist);
  k_thresh<<<(BATCH * NCLS + 255) / 256, 256, 0, stream>>>(hist, thresh);
  k_gather<<<dim3(32, BATCH), 256, 0, stream>>>(pred, thresh, counts, cand);
  k_nms   <<<BATCH * NCLS, 256, 0, stream>>>(pred, counts, cand, rows);
  k_final <<<BATCH, 256, 0, stream>>>(rows, out);
}